// Round 5
// baseline (224.385 us; speedup 1.0000x reference)
//
#include <hip/hip_runtime.h>
#include <math.h>

#define SEQ 512
#define FDIM 64
#define D 8
#define S2F 0.51011882f   // (1/sqrt(8)) * log2(e), folded into q at K1

// ---------------- K1: per-row projection: proj, q (folded), k ----------------
__global__ __launch_bounds__(256) void k1_project(
    const float* __restrict__ state,    // [B*S, F]
    const float* __restrict__ proj_w,   // [F, D]
    const float* __restrict__ proj_b,   // [D]
    const float* __restrict__ rotation, // [D, D]
    const float* __restrict__ entangle, // [D, D]
    float* __restrict__ Qw,             // [B*S, D]  (pre-scaled)
    float* __restrict__ Kw,             // [B*S, D]
    float* __restrict__ Pw,             // [B*S, D]
    int nrows)
{
    __shared__ float s_pw[FDIM][D];
    __shared__ float s_rot[D][D];
    __shared__ float s_ent[D][D];
    __shared__ float s_pb[D];

    const int tid = threadIdx.x;
    for (int i = tid; i < FDIM * D; i += 256) s_pw[i >> 3][i & 7] = proj_w[i];
    if (tid < D * D) { s_rot[tid >> 3][tid & 7] = rotation[tid];
                       s_ent[tid >> 3][tid & 7] = entangle[tid]; }
    if (tid < D) s_pb[tid] = proj_b[tid];
    __syncthreads();

    const int r = blockIdx.x * 256 + tid;
    if (r >= nrows) return;

    float pj[D];
    #pragma unroll
    for (int j = 0; j < D; j++) pj[j] = s_pb[j];

    const float4* sr = (const float4*)(state + (size_t)r * FDIM);
    #pragma unroll
    for (int c = 0; c < FDIM / 4; c++) {
        float4 v = sr[c];
        float vs[4] = {v.x, v.y, v.z, v.w};
        #pragma unroll
        for (int u = 0; u < 4; u++) {
            #pragma unroll
            for (int j = 0; j < D; j++) pj[j] += vs[u] * s_pw[c * 4 + u][j];
        }
    }

    float qv[D], kv[D];
    #pragma unroll
    for (int j = 0; j < D; j++) {
        float aq = 0.f, ak = 0.f;
        #pragma unroll
        for (int i = 0; i < D; i++) {
            aq += pj[i] * s_rot[i][j];
            ak += pj[i] * s_ent[i][j];
        }
        qv[j] = aq * S2F;   // fold softmax scale + log2e into q
        kv[j] = ak;
    }

    float4* Qp = (float4*)(Qw + (size_t)r * D);
    float4* Kp = (float4*)(Kw + (size_t)r * D);
    float4* Pp = (float4*)(Pw + (size_t)r * D);
    Qp[0] = make_float4(qv[0], qv[1], qv[2], qv[3]);
    Qp[1] = make_float4(qv[4], qv[5], qv[6], qv[7]);
    Kp[0] = make_float4(kv[0], kv[1], kv[2], kv[3]);
    Kp[1] = make_float4(kv[4], kv[5], kv[6], kv[7]);
    Pp[0] = make_float4(pj[0], pj[1], pj[2], pj[3]);
    Pp[1] = make_float4(pj[4], pj[5], pj[6], pj[7]);
}

// ---------------- K2: per (batch, t-half) attention partials ----------------
// block = b*2 + h; 8 waves: g = w&1 (query half), c = w>>1 (t quarter, 64 t).
// Each thread: 4 queries (g*256 + L + j*64), one 64-t quarter.
// Exact per-chunk max (pass A), exp2 accumulate (pass B), flash partials out.
__global__ __launch_bounds__(512, 4) void k2_attn(
    const float* __restrict__ Qw,
    const float* __restrict__ Kw,
    const float* __restrict__ Pw,
    float* __restrict__ PART)           // [B*2, SEQ, 10]: m, l, acc[8]
{
    __shared__ __align__(16) float s_k[256][D];      // 8 KB
    __shared__ __align__(16) float s_p[256][D];      // 8 KB
    __shared__ float s_cmax[SEQ][4];                 // 8 KB
    __shared__ float s_part[SEQ][9];                 // 18 KB
    const int blk = blockIdx.x;
    const int b   = blk >> 1;
    const int h   = blk & 1;
    const int tid = threadIdx.x;

    // stage this chunk's K,V rows (256 rows x 8 floats = 512 float4 each)
    const size_t base = ((size_t)b * SEQ + h * 256) * D;
    ((float4*)s_k)[tid] = ((const float4*)(Kw + base))[tid];
    ((float4*)s_p)[tid] = ((const float4*)(Pw + base))[tid];
    #pragma unroll
    for (int f = 0; f < 9; f++) s_part[tid][f] = 0.f;
    __syncthreads();

    const int L = tid & 63;
    const int w = tid >> 6;
    const int g = w & 1;          // query half
    const int c = w >> 1;         // t quarter
    const int q0 = g * 256 + L;   // queries q0 + j*64
    const int tb = c * 64;

    // load 4 query fragments from global (L2-resident after K1)
    float qf[4][D];
    #pragma unroll
    for (int j = 0; j < 4; j++) {
        const float4* qp = (const float4*)(Qw + ((size_t)b * SEQ + q0 + j * 64) * D);
        float4 a = qp[0], bb = qp[1];
        qf[j][0] = a.x;  qf[j][1] = a.y;  qf[j][2] = a.z;  qf[j][3] = a.w;
        qf[j][4] = bb.x; qf[j][5] = bb.y; qf[j][6] = bb.z; qf[j][7] = bb.w;
    }

    // ---- pass A: exact per-(query, quarter) max ----
    float mx[4] = {-1e30f, -1e30f, -1e30f, -1e30f};
    #pragma unroll 2
    for (int i = 0; i < 64; i++) {
        const float4* kt = (const float4*)s_k[tb + i];   // wave-uniform broadcast
        float4 k0 = kt[0], k1 = kt[1];
        #pragma unroll
        for (int j = 0; j < 4; j++) {
            float sc = qf[j][0]*k0.x + qf[j][1]*k0.y + qf[j][2]*k0.z + qf[j][3]*k0.w
                     + qf[j][4]*k1.x + qf[j][5]*k1.y + qf[j][6]*k1.z + qf[j][7]*k1.w;
            mx[j] = fmaxf(mx[j], sc);
        }
    }
    #pragma unroll
    for (int j = 0; j < 4; j++) s_cmax[q0 + j * 64][c] = mx[j];
    __syncthreads();

    // per-chunk max over the 4 quarters
    float mq[4];
    #pragma unroll
    for (int j = 0; j < 4; j++) {
        const int qr = q0 + j * 64;
        mq[j] = fmaxf(fmaxf(s_cmax[qr][0], s_cmax[qr][1]),
                      fmaxf(s_cmax[qr][2], s_cmax[qr][3]));
    }

    // ---- pass B: p = 2^(sc - m_chunk), accumulate l and p*V ----
    float l[4] = {0.f, 0.f, 0.f, 0.f};
    float acc[4][D];
    #pragma unroll
    for (int j = 0; j < 4; j++)
        #pragma unroll
        for (int d2 = 0; d2 < D; d2++) acc[j][d2] = 0.f;

    #pragma unroll 2
    for (int i = 0; i < 64; i++) {
        const int t = tb + i;
        const float4* kt = (const float4*)s_k[t];
        const float4* pt = (const float4*)s_p[t];
        float4 k0 = kt[0], k1 = kt[1];
        float4 p0 = pt[0], p1 = pt[1];
        #pragma unroll
        for (int j = 0; j < 4; j++) {
            float sc = qf[j][0]*k0.x + qf[j][1]*k0.y + qf[j][2]*k0.z + qf[j][3]*k0.w
                     + qf[j][4]*k1.x + qf[j][5]*k1.y + qf[j][6]*k1.z + qf[j][7]*k1.w;
            float p = exp2f(sc - mq[j]);        // exact: sc <= mq, no clamp needed
            l[j] += p;
            acc[j][0] += p * p0.x; acc[j][1] += p * p0.y;
            acc[j][2] += p * p0.z; acc[j][3] += p * p0.w;
            acc[j][4] += p * p1.x; acc[j][5] += p * p1.y;
            acc[j][6] += p * p1.z; acc[j][7] += p * p1.w;
        }
    }

    #pragma unroll
    for (int j = 0; j < 4; j++) {
        const int qr = q0 + j * 64;
        atomicAdd(&s_part[qr][0], l[j]);
        #pragma unroll
        for (int d2 = 0; d2 < D; d2++) atomicAdd(&s_part[qr][1 + d2], acc[j][d2]);
    }
    __syncthreads();

    // ---- write flash partial for query `tid`: [m, l, acc*8] ----
    const float m = fmaxf(fmaxf(s_cmax[tid][0], s_cmax[tid][1]),
                          fmaxf(s_cmax[tid][2], s_cmax[tid][3]));
    float* pr = PART + ((size_t)blk * SEQ + tid) * 10;
    pr[0] = m;
    pr[1] = s_part[tid][0];
    #pragma unroll
    for (int d2 = 0; d2 < D; d2++) pr[2 + d2] = s_part[tid][1 + d2];
}

// ---------------- K3: merge 2 chunks + normalize + MLP head ----------------
__global__ __launch_bounds__(512) void k3_mlp(
    const float* __restrict__ PART,
    const float* __restrict__ w1, const float* __restrict__ b1,
    const float* __restrict__ w2, const float* __restrict__ b2,
    const float* __restrict__ w3, const float* __restrict__ b3,
    float* __restrict__ out)
{
    __shared__ float s_w1[D * 32];
    __shared__ float s_b1[32];
    __shared__ float s_w2[32 * 16];
    __shared__ float s_b2[16];
    __shared__ float s_w3[16];
    __shared__ float s_b3[1];

    const int tid = threadIdx.x;
    if (tid < D * 32)  s_w1[tid] = w1[tid];
    if (tid < 32)      s_b1[tid] = b1[tid];
    if (tid < 32 * 16) s_w2[tid] = w2[tid];
    if (tid < 16)      s_b2[tid] = b2[tid];
    if (tid < 16)      s_w3[tid] = w3[tid];
    if (tid == 0)      s_b3[0]   = b3[0];
    __syncthreads();

    const int b = blockIdx.x;
    const float* p0 = PART + (((size_t)b * 2 + 0) * SEQ + tid) * 10;
    const float* p1 = PART + (((size_t)b * 2 + 1) * SEQ + tid) * 10;

    const float m0 = p0[0], l0 = p0[1];
    const float m1 = p1[0], l1 = p1[1];
    const float m  = fmaxf(m0, m1);
    const float a0 = exp2f(m0 - m);
    const float a1 = exp2f(m1 - m);
    const float inv_l = 1.0f / (l0 * a0 + l1 * a1);

    float attn[D];
    #pragma unroll
    for (int d2 = 0; d2 < D; d2++)
        attn[d2] = (p0[2 + d2] * a0 + p1[2 + d2] * a1) * inv_l;

    float h1[32];
    #pragma unroll
    for (int j = 0; j < 32; j++) {
        float a = s_b1[j];
        #pragma unroll
        for (int i = 0; i < D; i++) a += attn[i] * s_w1[i * 32 + j];
        h1[j] = fmaxf(a, 0.f);
    }
    float h2[16];
    #pragma unroll
    for (int j = 0; j < 16; j++) {
        float a = s_b2[j];
        #pragma unroll
        for (int i = 0; i < 32; i++) a += h1[i] * s_w2[i * 16 + j];
        h2[j] = fmaxf(a, 0.f);
    }
    float o = s_b3[0];
    #pragma unroll
    for (int i = 0; i < 16; i++) o += h2[i] * s_w3[i];

    out[(size_t)b * SEQ + tid] = o;
}

extern "C" void kernel_launch(void* const* d_in, const int* in_sizes, int n_in,
                              void* d_out, int out_size, void* d_ws, size_t ws_size,
                              hipStream_t stream) {
    const float* state    = (const float*)d_in[0];
    const float* proj_w   = (const float*)d_in[1];
    const float* proj_b   = (const float*)d_in[2];
    const float* rotation = (const float*)d_in[3];
    const float* entangle = (const float*)d_in[4];
    const float* w1       = (const float*)d_in[5];
    const float* b1       = (const float*)d_in[6];
    const float* w2       = (const float*)d_in[7];
    const float* b2       = (const float*)d_in[8];
    const float* w3       = (const float*)d_in[9];
    const float* b3       = (const float*)d_in[10];
    float* out = (float*)d_out;

    const int B     = in_sizes[0] / (SEQ * FDIM);   // 256
    const int nrows = B * SEQ;                      // 131072

    // workspace layout (floats): Q | K | P | PART
    float* Qw   = (float*)d_ws;
    float* Kw   = Qw + (size_t)nrows * D;
    float* Pw   = Kw + (size_t)nrows * D;
    float* PART = Pw + (size_t)nrows * D;           // B*2*SEQ*10 floats

    k1_project<<<nrows / 256, 256, 0, stream>>>(
        state, proj_w, proj_b, rotation, entangle, Qw, Kw, Pw, nrows);
    k2_attn<<<B * 2, 512, 0, stream>>>(Qw, Kw, Pw, PART);
    k3_mlp<<<B, 512, 0, stream>>>(PART, w1, b1, w2, b2, w3, b3, out);
}

// Round 6
// 190.756 us; speedup vs baseline: 1.1763x; 1.1763x over previous
//
#include <hip/hip_runtime.h>
#include <math.h>

#define SEQ 512
#define FDIM 64
#define D 8
#define S2F 0.51011882f   // (1/sqrt(8)) * log2(e), folded into q at K1
#define NCH 2
#define CHLEN (SEQ / NCH) // 256

// ---- K1: quad-cooperative projection (coalesced-ish, 4 lanes per row) ----
__global__ __launch_bounds__(256) void k1_project(
    const float* __restrict__ state,    // [B*S, F]
    const float* __restrict__ proj_w,   // [F, D]
    const float* __restrict__ proj_b,   // [D]
    const float* __restrict__ rotation, // [D, D]
    const float* __restrict__ entangle, // [D, D]
    float* __restrict__ Qw, float* __restrict__ Kw, float* __restrict__ Pw)
{
    __shared__ __align__(16) float s_pw[FDIM][D];
    __shared__ __align__(16) float s_rot[D][D];
    __shared__ __align__(16) float s_ent[D][D];
    __shared__ float s_pb[D];
    const int tid = threadIdx.x;
    for (int i = tid; i < FDIM * D; i += 256) s_pw[i >> 3][i & 7] = proj_w[i];
    if (tid < D * D) { s_rot[tid >> 3][tid & 7] = rotation[tid];
                       s_ent[tid >> 3][tid & 7] = entangle[tid]; }
    if (tid < D) s_pb[tid] = proj_b[tid];
    __syncthreads();

    const int r = blockIdx.x * 64 + (tid >> 2);  // row: 64 rows per block
    const int c = tid & 3;                       // quarter of the row

    const float4* sp = (const float4*)(state + (size_t)r * FDIM + c * 16);
    float4 v0 = sp[0], v1 = sp[1], v2 = sp[2], v3 = sp[3];
    float sv[16];
    sv[0]=v0.x; sv[1]=v0.y; sv[2]=v0.z; sv[3]=v0.w;
    sv[4]=v1.x; sv[5]=v1.y; sv[6]=v1.z; sv[7]=v1.w;
    sv[8]=v2.x; sv[9]=v2.y; sv[10]=v2.z; sv[11]=v2.w;
    sv[12]=v3.x; sv[13]=v3.y; sv[14]=v3.z; sv[15]=v3.w;

    float pj[D] = {0,0,0,0,0,0,0,0};
    #pragma unroll
    for (int u = 0; u < 16; u++) {
        const int wr = c * 16 + u;
        float4 w0 = *(const float4*)&s_pw[wr][0];
        float4 w1 = *(const float4*)&s_pw[wr][4];
        const float s = sv[u];
        pj[0] += s * w0.x; pj[1] += s * w0.y; pj[2] += s * w0.z; pj[3] += s * w0.w;
        pj[4] += s * w1.x; pj[5] += s * w1.y; pj[6] += s * w1.z; pj[7] += s * w1.w;
    }
    // quad reduce (xor 1, xor 2) -> all 4 lanes hold full row dot; add bias once
    #pragma unroll
    for (int j = 0; j < D; j++) {
        pj[j] += __shfl_xor(pj[j], 1, 64);
        pj[j] += __shfl_xor(pj[j], 2, 64);
        pj[j] += s_pb[j];
    }

    float qv[D] = {0,0,0,0,0,0,0,0};
    float kv[D] = {0,0,0,0,0,0,0,0};
    #pragma unroll
    for (int i = 0; i < D; i++) {
        float4 r0 = *(const float4*)&s_rot[i][0];
        float4 r1 = *(const float4*)&s_rot[i][4];
        float4 e0 = *(const float4*)&s_ent[i][0];
        float4 e1 = *(const float4*)&s_ent[i][4];
        const float p = pj[i];
        qv[0] += p * r0.x; qv[1] += p * r0.y; qv[2] += p * r0.z; qv[3] += p * r0.w;
        qv[4] += p * r1.x; qv[5] += p * r1.y; qv[6] += p * r1.z; qv[7] += p * r1.w;
        kv[0] += p * e0.x; kv[1] += p * e0.y; kv[2] += p * e0.z; kv[3] += p * e0.w;
        kv[4] += p * e1.x; kv[5] += p * e1.y; kv[6] += p * e1.z; kv[7] += p * e1.w;
    }
    if (c == 0) {
        float4* Qp = (float4*)(Qw + (size_t)r * D);
        Qp[0] = make_float4(qv[0]*S2F, qv[1]*S2F, qv[2]*S2F, qv[3]*S2F);
        Qp[1] = make_float4(qv[4]*S2F, qv[5]*S2F, qv[6]*S2F, qv[7]*S2F);
    } else if (c == 1) {
        float4* Kp = (float4*)(Kw + (size_t)r * D);
        Kp[0] = make_float4(kv[0], kv[1], kv[2], kv[3]);
        Kp[1] = make_float4(kv[4], kv[5], kv[6], kv[7]);
    } else if (c == 2) {
        float4* Pp = (float4*)(Pw + (size_t)r * D);
        Pp[0] = make_float4(pj[0], pj[1], pj[2], pj[3]);
        Pp[1] = make_float4(pj[4], pj[5], pj[6], pj[7]);
    }
}

// ---- K2: per (batch, t-half); thread owns 2 queries over 256 keys ----
// All state in explicit float4 registers; no arrays, no atomics, no s_part.
__global__ __launch_bounds__(256) void k2_attn(
    const float* __restrict__ Qw, const float* __restrict__ Kw,
    const float* __restrict__ Pw, float* __restrict__ PART) // [B*2, SEQ, 10]
{
    __shared__ __align__(16) float4 s_k[CHLEN * 2];   // 8 KB
    __shared__ __align__(16) float4 s_p[CHLEN * 2];   // 8 KB
    const int blk = blockIdx.x, b = blk >> 1, h = blk & 1, tid = threadIdx.x;

    const size_t base = ((size_t)b * SEQ + h * CHLEN) * D;
    const float4* kg = (const float4*)(Kw + base);
    const float4* pg = (const float4*)(Pw + base);
    s_k[tid] = kg[tid]; s_k[tid + 256] = kg[tid + 256];
    s_p[tid] = pg[tid]; s_p[tid + 256] = pg[tid + 256];
    __syncthreads();

    const float4* qp0 = (const float4*)(Qw + ((size_t)b * SEQ + tid) * D);
    const float4* qp1 = (const float4*)(Qw + ((size_t)b * SEQ + tid + 256) * D);
    const float4 qa0 = qp0[0], qa1 = qp0[1];
    const float4 qb0 = qp1[0], qb1 = qp1[1];

    // pass A: exact per-(query, half) max
    float m0 = -1e30f, m1 = -1e30f;
    #pragma unroll 4
    for (int t = 0; t < CHLEN; t++) {
        const float4 k0 = s_k[2 * t], k1 = s_k[2 * t + 1];
        float s0 = qa0.x*k0.x + qa0.y*k0.y + qa0.z*k0.z + qa0.w*k0.w
                 + qa1.x*k1.x + qa1.y*k1.y + qa1.z*k1.z + qa1.w*k1.w;
        float s1 = qb0.x*k0.x + qb0.y*k0.y + qb0.z*k0.z + qb0.w*k0.w
                 + qb1.x*k1.x + qb1.y*k1.y + qb1.z*k1.z + qb1.w*k1.w;
        m0 = fmaxf(m0, s0); m1 = fmaxf(m1, s1);
    }

    // pass B: p = 2^(sc - m), accumulate l and p*V
    float l0 = 0.f, l1 = 0.f;
    float4 a00 = {0,0,0,0}, a01 = {0,0,0,0};
    float4 a10 = {0,0,0,0}, a11 = {0,0,0,0};
    #pragma unroll 2
    for (int t = 0; t < CHLEN; t++) {
        const float4 k0 = s_k[2 * t], k1 = s_k[2 * t + 1];
        const float4 p0 = s_p[2 * t], p1 = s_p[2 * t + 1];
        float s0 = qa0.x*k0.x + qa0.y*k0.y + qa0.z*k0.z + qa0.w*k0.w
                 + qa1.x*k1.x + qa1.y*k1.y + qa1.z*k1.z + qa1.w*k1.w;
        float s1 = qb0.x*k0.x + qb0.y*k0.y + qb0.z*k0.z + qb0.w*k0.w
                 + qb1.x*k1.x + qb1.y*k1.y + qb1.z*k1.z + qb1.w*k1.w;
        const float e0 = exp2f(s0 - m0);
        const float e1 = exp2f(s1 - m1);
        l0 += e0; l1 += e1;
        a00.x += e0*p0.x; a00.y += e0*p0.y; a00.z += e0*p0.z; a00.w += e0*p0.w;
        a01.x += e0*p1.x; a01.y += e0*p1.y; a01.z += e0*p1.z; a01.w += e0*p1.w;
        a10.x += e1*p0.x; a10.y += e1*p0.y; a10.z += e1*p0.z; a10.w += e1*p0.w;
        a11.x += e1*p1.x; a11.y += e1*p1.y; a11.z += e1*p1.z; a11.w += e1*p1.w;
    }

    float* pr0 = PART + ((size_t)blk * SEQ + tid) * 10;
    pr0[0]=m0; pr0[1]=l0;
    pr0[2]=a00.x; pr0[3]=a00.y; pr0[4]=a00.z; pr0[5]=a00.w;
    pr0[6]=a01.x; pr0[7]=a01.y; pr0[8]=a01.z; pr0[9]=a01.w;
    float* pr1 = PART + ((size_t)blk * SEQ + tid + 256) * 10;
    pr1[0]=m1; pr1[1]=l1;
    pr1[2]=a10.x; pr1[3]=a10.y; pr1[4]=a10.z; pr1[5]=a10.w;
    pr1[6]=a11.x; pr1[7]=a11.y; pr1[8]=a11.z; pr1[9]=a11.w;
}

// ---- K3: merge 2 halves + normalize + MLP head ----
__global__ __launch_bounds__(512) void k3_mlp(
    const float* __restrict__ PART,
    const float* __restrict__ w1, const float* __restrict__ b1,
    const float* __restrict__ w2, const float* __restrict__ b2,
    const float* __restrict__ w3, const float* __restrict__ b3,
    float* __restrict__ out)
{
    __shared__ float s_w1[D * 32];
    __shared__ float s_b1[32];
    __shared__ float s_w2[32 * 16];
    __shared__ float s_b2[16];
    __shared__ float s_w3[16];
    __shared__ float s_b3[1];
    const int tid = threadIdx.x;
    if (tid < D * 32)  s_w1[tid] = w1[tid];
    if (tid < 32)      s_b1[tid] = b1[tid];
    if (tid < 32 * 16) s_w2[tid] = w2[tid];
    if (tid < 16)      s_b2[tid] = b2[tid];
    if (tid < 16)      s_w3[tid] = w3[tid];
    if (tid == 0)      s_b3[0]   = b3[0];
    __syncthreads();

    const int b = blockIdx.x;
    const float* p0 = PART + (((size_t)b * 2 + 0) * SEQ + tid) * 10;
    const float* p1 = PART + (((size_t)b * 2 + 1) * SEQ + tid) * 10;

    const float m0 = p0[0], l0 = p0[1];
    const float m1 = p1[0], l1 = p1[1];
    const float m  = fmaxf(m0, m1);
    const float a0 = exp2f(m0 - m);
    const float a1 = exp2f(m1 - m);
    const float inv_l = 1.0f / (l0 * a0 + l1 * a1);

    float attn[D];
    #pragma unroll
    for (int d2 = 0; d2 < D; d2++)
        attn[d2] = (p0[2 + d2] * a0 + p1[2 + d2] * a1) * inv_l;

    float h1[32];
    #pragma unroll
    for (int j = 0; j < 32; j++) {
        float a = s_b1[j];
        #pragma unroll
        for (int i = 0; i < D; i++) a += attn[i] * s_w1[i * 32 + j];
        h1[j] = fmaxf(a, 0.f);
    }
    float h2[16];
    #pragma unroll
    for (int j = 0; j < 16; j++) {
        float a = s_b2[j];
        #pragma unroll
        for (int i = 0; i < 32; i++) a += h1[i] * s_w2[i * 16 + j];
        h2[j] = fmaxf(a, 0.f);
    }
    float o = s_b3[0];
    #pragma unroll
    for (int i = 0; i < 16; i++) o += h2[i] * s_w3[i];

    out[(size_t)b * SEQ + tid] = o;
}

extern "C" void kernel_launch(void* const* d_in, const int* in_sizes, int n_in,
                              void* d_out, int out_size, void* d_ws, size_t ws_size,
                              hipStream_t stream) {
    const float* state    = (const float*)d_in[0];
    const float* proj_w   = (const float*)d_in[1];
    const float* proj_b   = (const float*)d_in[2];
    const float* rotation = (const float*)d_in[3];
    const float* entangle = (const float*)d_in[4];
    const float* w1       = (const float*)d_in[5];
    const float* b1       = (const float*)d_in[6];
    const float* w2       = (const float*)d_in[7];
    const float* b2       = (const float*)d_in[8];
    const float* w3       = (const float*)d_in[9];
    const float* b3       = (const float*)d_in[10];
    float* out = (float*)d_out;

    const int B     = in_sizes[0] / (SEQ * FDIM);   // 256
    const int nrows = B * SEQ;                      // 131072

    float* Qw   = (float*)d_ws;
    float* Kw   = Qw + (size_t)nrows * D;
    float* Pw   = Kw + (size_t)nrows * D;
    float* PART = Pw + (size_t)nrows * D;           // B*2*SEQ*10 floats

    k1_project<<<nrows / 64, 256, 0, stream>>>(
        state, proj_w, proj_b, rotation, entangle, Qw, Kw, Pw);
    k2_attn<<<B * NCH, 256, 0, stream>>>(Qw, Kw, Pw, PART);
    k3_mlp<<<B, 512, 0, stream>>>(PART, w1, b1, w2, b2, w3, b3, out);
}